// Round 6
// baseline (319.321 us; speedup 1.0000x reference)
//
#include <hip/hip_runtime.h>
#include <hip/hip_bf16.h>
#include <stdint.h>

#define B_SZ 8192
#define D_SZ 1024
#define O_SZ 1024
#define E_SZ 8

typedef __bf16 bf16_t;
typedef __bf16 bf16x8 __attribute__((ext_vector_type(8)));
typedef __bf16 bf16x4 __attribute__((ext_vector_type(4)));
typedef float  f32x4  __attribute__((ext_vector_type(4)));

// ---- fused prep ----
// blocks [0, 2048):    gating softmax(x@Wg+bg) + x fp32->bf16 (4 rows/block)
// blocks [2048, 4096): We [E,D,O] fp32 -> WeT [E,O,D] bf16 (vectorized)
__global__ __launch_bounds__(256) void prep_kernel(
    const float* __restrict__ x, const float* __restrict__ Wg,
    const float* __restrict__ bg, const float* __restrict__ We,
    float* __restrict__ gates, bf16_t* __restrict__ xb,
    bf16_t* __restrict__ WeT) {
  __shared__ float tile[64][65];
  const int tid = threadIdx.x;
  if (blockIdx.x < 2048) {
    const int w = tid >> 6, lane = tid & 63;
    const int b = blockIdx.x * 4 + w;
    const float* xr = x + (size_t)b * D_SZ;
    float acc[8];
#pragma unroll
    for (int e = 0; e < 8; ++e) acc[e] = 0.f;
    float xs[16];
#pragma unroll
    for (int it = 0; it < 4; ++it) {
      const int d = it * 256 + lane * 4;
      float4 xv = *(const float4*)(xr + d);
      xs[it * 4 + 0] = xv.x; xs[it * 4 + 1] = xv.y;
      xs[it * 4 + 2] = xv.z; xs[it * 4 + 3] = xv.w;
#pragma unroll
      for (int j = 0; j < 4; ++j) {
        const float4* wr = (const float4*)(Wg + (size_t)(d + j) * 8);
        float4 w0 = wr[0], w1 = wr[1];
        float xj = xs[it * 4 + j];
        acc[0] += xj * w0.x; acc[1] += xj * w0.y;
        acc[2] += xj * w0.z; acc[3] += xj * w0.w;
        acc[4] += xj * w1.x; acc[5] += xj * w1.y;
        acc[6] += xj * w1.z; acc[7] += xj * w1.w;
      }
    }
#pragma unroll
    for (int off = 32; off >= 1; off >>= 1) {
#pragma unroll
      for (int e = 0; e < 8; ++e) acc[e] += __shfl_xor(acc[e], off, 64);
    }
    float g[8];
#pragma unroll
    for (int e = 0; e < 8; ++e) g[e] = acc[e] + bg[e];
    float m = g[0];
#pragma unroll
    for (int e = 1; e < 8; ++e) m = fmaxf(m, g[e]);
    float s = 0.f;
#pragma unroll
    for (int e = 0; e < 8; ++e) { g[e] = __expf(g[e] - m); s += g[e]; }
    float inv = 1.0f / s;
    if (lane == 0) {
      float* gr = gates + (size_t)b * 8;
#pragma unroll
      for (int e = 0; e < 8; ++e) gr[e] = g[e] * inv;
    }
    bf16_t* ar = xb + (size_t)b * D_SZ;
#pragma unroll
    for (int it = 0; it < 4; ++it) {
      const int d = it * 256 + lane * 4;
      bf16x4 ov;
      ov[0] = (bf16_t)xs[it * 4 + 0]; ov[1] = (bf16_t)xs[it * 4 + 1];
      ov[2] = (bf16_t)xs[it * 4 + 2]; ov[3] = (bf16_t)xs[it * 4 + 3];
      *(bf16x4*)(ar + d) = ov;
    }
  } else {
    const int tb = blockIdx.x - 2048;
    const int e = tb >> 8, rem = tb & 255;
    const int d0 = (rem >> 4) << 6, o0 = (rem & 15) << 6;
    const float* src = We + (size_t)e * D_SZ * O_SZ + (size_t)d0 * O_SZ + o0;
#pragma unroll
    for (int p = 0; p < 4; ++p) {
      const int d = p * 16 + (tid >> 4);
      const int o = (tid & 15) * 4;
      float4 v = *(const float4*)(src + (size_t)d * O_SZ + o);
      tile[d][o] = v.x; tile[d][o + 1] = v.y;
      tile[d][o + 2] = v.z; tile[d][o + 3] = v.w;
    }
    __syncthreads();
    bf16_t* dstp = WeT + (size_t)e * O_SZ * D_SZ + (size_t)o0 * D_SZ + d0;
#pragma unroll
    for (int p = 0; p < 2; ++p) {
      const int o = p * 32 + (tid >> 3);
      const int d8 = (tid & 7) * 8;
      bf16x8 ov;
#pragma unroll
      for (int k = 0; k < 8; ++k) ov[k] = (bf16_t)tile[d8 + k][o];
      *(bf16x8*)(dstp + (size_t)o * D_SZ + d8) = ov;
    }
  }
}

// ---------------- fused expert GEMM + gate combine ----------------
// Software-pipelined K-loop: double-buffered LDS, loads issued one K-step
// ahead via global_load_lds, waited with vmcnt(4) (never a full drain),
// raw s_barrier via asm so the compiler cannot insert s_waitcnt vmcnt(0).
__device__ __forceinline__ void gload_lds16(const bf16_t* g, char* l) {
  __builtin_amdgcn_global_load_lds(
      (const __attribute__((address_space(1))) void*)g,
      (__attribute__((address_space(3))) void*)l, 16, 0, 0);
}

#define RAW_BARRIER() asm volatile("s_barrier" ::: "memory")
#define WAIT_VM4()    asm volatile("s_waitcnt vmcnt(4)" ::: "memory")
#define WAIT_LGKM0()  asm volatile("s_waitcnt lgkmcnt(0)" ::: "memory")

__global__ __launch_bounds__(256, 2) void moe_gemm(
    const bf16_t* __restrict__ xb,    // [B, D] bf16
    const bf16_t* __restrict__ wet,   // [E, O, D] bf16
    const float* __restrict__ gates,  // [B, E]
    const float* __restrict__ be,     // [E, O]
    float* __restrict__ out)          // [B, O]
{
  __shared__ bf16_t lA[2][128 * 32];  // 2 x 8 KB, XOR-swizzled 16B granules
  __shared__ bf16_t lB[2][128 * 32];  // 2 x 8 KB
  __shared__ float  lG[128 * 8];      // 4 KB gates for this row-tile

  const int tid = threadIdx.x;
  const int b0 = blockIdx.y * 128;
  const int o0 = blockIdx.x * 128;

  {  // stage gates; make visible to all waves before the K loop
    const float* gsrc = gates + (size_t)b0 * 8;
#pragma unroll
    for (int i = 0; i < 4; ++i) lG[tid + 256 * i] = gsrc[tid + 256 * i];
  }

  const int w = tid >> 6;
  const int lane = tid & 63;
  const int wm = (w >> 1) * 64;
  const int wn = (w & 1) * 64;
  const int m16 = lane & 15;
  const int q = lane >> 4;

  // staging: granule gi covers row gi>>2, slot = (gi&3)^((row>>1)&3)
  const int gi0 = tid, gi1 = tid + 256;
  const int ar0 = gi0 >> 2, ac0 = (((gi0 & 3) ^ ((gi0 >> 3) & 3)) * 8);
  const int ar1 = gi1 >> 2, ac1 = (((gi1 & 3) ^ ((gi1 >> 3) & 3)) * 8);
  const int la0off = (w * 64) * 16;          // byte offsets inside a buffer
  const int la1off = (256 + w * 64) * 16;

  const bf16_t* Abase = xb + (size_t)b0 * D_SZ;
  const bf16_t* Wbase = wet + (size_t)o0 * D_SZ;  // + e*O*D per expert

  f32x4 outAcc[4][4];
#pragma unroll
  for (int i = 0; i < 4; ++i)
#pragma unroll
    for (int j = 0; j < 4; ++j) outAcc[i][j] = f32x4{0.f, 0.f, 0.f, 0.f};

  // make lG writes visible before any wave reads them (epilogue folds)
  WAIT_LGKM0();
  RAW_BARRIER();

  // prologue: issue batch s=0 into buffer 0
  {
    const bf16_t* Bb = Wbase;  // e=0, kc=0
    gload_lds16(Abase + (size_t)ar0 * D_SZ + ac0, (char*)lA[0] + la0off);
    gload_lds16(Abase + (size_t)ar1 * D_SZ + ac1, (char*)lA[0] + la1off);
    gload_lds16(Bb + (size_t)ar0 * D_SZ + ac0, (char*)lB[0] + la0off);
    gload_lds16(Bb + (size_t)ar1 * D_SZ + ac1, (char*)lB[0] + la1off);
  }

  f32x4 acc[4][4];
#pragma unroll
  for (int i = 0; i < 4; ++i)
#pragma unroll
    for (int j = 0; j < 4; ++j) acc[i][j] = f32x4{0.f, 0.f, 0.f, 0.f};

  for (int s = 0; s < E_SZ * (D_SZ / 32); ++s) {
    const int e = s >> 5;
    const int par = s & 1;

    // barrier #1: all waves done reading buf[par^1] (s-1's data) -> safe to
    // overwrite it with batch s+1.
    RAW_BARRIER();
    {
      const int sn = (s < 255) ? s + 1 : 255;
      const int en = sn >> 5, kn = (sn & 31) * 32;
      const int pn = sn & 1;
      const bf16_t* An = Abase + kn;
      const bf16_t* Bn = Wbase + (size_t)en * (O_SZ * D_SZ) + kn;
      gload_lds16(An + (size_t)ar0 * D_SZ + ac0, (char*)lA[pn] + la0off);
      gload_lds16(An + (size_t)ar1 * D_SZ + ac1, (char*)lA[pn] + la1off);
      gload_lds16(Bn + (size_t)ar0 * D_SZ + ac0, (char*)lB[pn] + la0off);
      gload_lds16(Bn + (size_t)ar1 * D_SZ + ac1, (char*)lB[pn] + la1off);
    }
    // wait for batch s (issued one step ago), leaving batch s+1 in flight
    WAIT_VM4();
    // barrier #2: every wave's batch-s data has landed in buf[par]
    RAW_BARRIER();

    bf16x8 af[4], bfr[4];
#pragma unroll
    for (int i = 0; i < 4; ++i) {
      int r = wm + i * 16 + m16;
      int pg = (q ^ ((r >> 1) & 3)) * 8;
      af[i] = *(const bf16x8*)&lA[par][r * 32 + pg];
    }
#pragma unroll
    for (int j = 0; j < 4; ++j) {
      int r = wn + j * 16 + m16;
      int pg = (q ^ ((r >> 1) & 3)) * 8;
      bfr[j] = *(const bf16x8*)&lB[par][r * 32 + pg];
    }
#pragma unroll
    for (int i = 0; i < 4; ++i)
#pragma unroll
      for (int j = 0; j < 4; ++j)
        acc[i][j] = __builtin_amdgcn_mfma_f32_16x16x32_bf16(
            af[i], bfr[j], acc[i][j], 0, 0, 0);

    if ((s & 31) == 31) {
      // fold expert e: outAcc += g[row,e] * (acc + be[e,col]); reset acc
#pragma unroll
      for (int j = 0; j < 4; ++j) {
        float bec = be[e * O_SZ + o0 + wn + j * 16 + m16];
#pragma unroll
        for (int i = 0; i < 4; ++i) {
#pragma unroll
          for (int rg = 0; rg < 4; ++rg) {
            float gv = lG[(wm + i * 16 + q * 4 + rg) * 8 + e];
            outAcc[i][j][rg] += gv * (acc[i][j][rg] + bec);
            acc[i][j][rg] = 0.f;
          }
        }
      }
    }
  }

#pragma unroll
  for (int i = 0; i < 4; ++i)
#pragma unroll
    for (int rg = 0; rg < 4; ++rg) {
      float* orow = out + (size_t)(b0 + wm + i * 16 + q * 4 + rg) * O_SZ
                    + o0 + wn + m16;
#pragma unroll
      for (int j = 0; j < 4; ++j) orow[j * 16] = outAcc[i][j][rg];
    }
}

extern "C" void kernel_launch(void* const* d_in, const int* in_sizes, int n_in,
                              void* d_out, int out_size, void* d_ws, size_t ws_size,
                              hipStream_t stream) {
  const float* x  = (const float*)d_in[0];
  const float* Wg = (const float*)d_in[1];
  const float* bg = (const float*)d_in[2];
  const float* We = (const float*)d_in[3];
  const float* be = (const float*)d_in[4];
  float* out = (float*)d_out;

  char* ws = (char*)d_ws;
  float*  gates = (float*)ws;                             // 256 KB
  bf16_t* xb    = (bf16_t*)(ws + (1 << 18));              // 16 MB
  bf16_t* wet   = (bf16_t*)(ws + (1 << 18) + (1 << 24));  // 16 MB

  prep_kernel<<<4096, 256, 0, stream>>>(x, Wg, bg, We, gates, xb, wet);
  moe_gemm<<<dim3(O_SZ / 128, B_SZ / 128), 256, 0, stream>>>(
      xb, wet, gates, be, out);
}